// Round 8
// baseline (251.395 us; speedup 1.0000x reference)
//
#include <hip/hip_runtime.h>

constexpr int NB = 8, NA = 64, NT = 12, NH = 128, NTY = 8, NSC = 32, NAG = 16;

struct Params {
    const float *traj, *ntraj, *ty, *sd, *adata, *rel;
    const float *W_in, *b_in, *W_nt, *b_nt, *W_ag, *b_ag, *W_sc, *b_sc;
    const float *W_ein, *b_ein, *W_ety, *b_ety;
    const float *W_edge, *b_edge, *W_self, *b_self, *W_e2n, *b_e2n;
    const float *W_ih, *W_hh, *b_ih, *b_hh, *W_pred, *b_pred;
    float *h0, *h1, *c, *se, *R;
    float *Wty, *Wsc, *Wag, *Wcomb, *vbase, *vag, *vbe, *sesty, *Xs, *out;
};

// ---- Prelude: fold (blk 0-184) | r0+sesty (blk 185-312, 4 rows/block) ----
// x layout for W_ih rows: [coord 0:128 | type 128:256 | node 256:384 | scene 384:512 | agent 512:640]
__global__ __launch_bounds__(512) void k_prelude(Params p) {
    const int blk = blockIdx.x, tid = threadIdx.x;
    if (blk < 185) {
        const int c = tid;
        __shared__ float lrow[NH];
        __shared__ float b1[NH], b2[NH], b3[NH], b4[NH];
        if (blk < 184) {
            const float* src; int ihoff, row; float* dst;
            if (blk < 8)       { row = blk;      src = p.W_nt  + row * NH; ihoff = 128; dst = p.Wty; }
            else if (blk < 40) { row = blk - 8;  src = p.W_sc  + row * NH; ihoff = 384; dst = p.Wsc; }
            else if (blk < 56) { row = blk - 40; src = p.W_ag  + row * NH; ihoff = 512; dst = p.Wag; }
            else               { row = blk - 56; src = p.W_e2n + row * NH; ihoff = 256; dst = p.Wcomb; }
            if (c < NH) lrow[c] = src[c];
            __syncthreads();
            float acc = 0.f;
            for (int k = 0; k < NH; ++k) acc += lrow[k] * p.W_ih[(ihoff + k) * 512 + c];
            dst[row * 512 + c] = acc;
        } else {
            if (c < NH) { b1[c] = p.b_nt[c]; b2[c] = p.b_sc[c]; b3[c] = p.b_ag[c]; b4[c] = p.b_e2n[c]; }
            __syncthreads();
            float vb = p.b_ih[c] + p.b_hh[c], va = 0.f, ve = 0.f;
            for (int k = 0; k < NH; ++k) {
                vb += b1[k] * p.W_ih[(128 + k) * 512 + c] + b2[k] * p.W_ih[(384 + k) * 512 + c];
                va += b3[k] * p.W_ih[(512 + k) * 512 + c];
                ve += b4[k] * p.W_ih[(256 + k) * 512 + c];
            }
            p.vbase[c] = vb; p.vag[c] = va; p.vbe[c] = ve;
        }
    } else {
        // R0 closed form + sesty, 4 rows/block.
        const int r0g = (blk - 185) * 4;
        const int b = r0g >> 6;
        const int q = tid >> 7, n = tid & 127;
        const int row = r0g + q, i = row & 63;
        __shared__ float lf[NA][6];
        __shared__ float lt[NA][NTY];
        __shared__ float sumf[6], sumt[NTY];
        if (tid < NA) {
            int j = tid, rj = b * NA + j;
            for (int k = 0; k < 3; ++k) {
                lf[j][k]     = p.ntraj[(rj * NT + 0) * 3 + k];
                lf[j][3 + k] = p.traj [(rj * NT + 0) * 3 + k];
            }
            for (int k = 0; k < NTY; ++k) lt[j][k] = p.ty[rj * NTY + k];
        }
        __syncthreads();
        if (tid < 6) {
            float s = 0.f; for (int j = 0; j < NA; ++j) s += lf[j][tid];
            sumf[tid] = s;
        } else if (tid < 6 + NTY) {
            int k = tid - 6; float s = 0.f;
            for (int j = 0; j < NA; ++j) s += lt[j][k];
            sumt[k] = s;
        }
        __syncthreads();
        float acc_i = p.b_ein[n] + p.b_ety[n];
        for (int k = 0; k < 6; ++k)   acc_i += lf[i][k] * p.W_ein[k * NH + n];
        for (int k = 0; k < NTY; ++k) acc_i += lt[i][k] * (p.W_ein[(12 + k) * NH + n] + p.W_ety[k * NH + n]);
        float acc_j = 0.f;
        for (int k = 0; k < 6; ++k)   acc_j += sumf[k] * p.W_ein[(6 + k) * NH + n];
        for (int k = 0; k < NTY; ++k) acc_j += sumt[k] * (p.W_ein[(20 + k) * NH + n] + p.W_ety[(NTY + k) * NH + n]);
        p.R[row * NH + n] = 64.f * acc_i + acc_j;
        float sv = p.b_self[n];
        for (int k = 0; k < NTY; ++k) sv += lt[i][k] * p.W_self[(2 * NH + k) * NH + n];
        p.sesty[row * NH + n] = sv;
    }
}

// ---- X_static[(g,t), 512]; vbe folded in for t>0 ----
__global__ __launch_bounds__(512) void k_xstatic(Params p) {
    const int g = blockIdx.x, tid = threadIdx.x, b = g >> 6;
    __shared__ float coordL[NT][NH];
    __shared__ float sceneL[NT][NSC];
    __shared__ float agentL[NT][NAG];
    __shared__ float tyL[NTY];
    const float relv = p.rel[g];
    for (int idx = tid; idx < NT * NH; idx += 512) {
        int r = idx >> 7, k = idx & 127;
        float acc = p.b_in[k];
        const float* nt = p.ntraj + (g * NT + r) * 3;
        const float* tr = p.traj  + (g * NT + r) * 3;
        for (int j = 0; j < 3; ++j) acc += nt[j] * p.W_in[j * NH + k] + tr[j] * p.W_in[(3 + j) * NH + k];
        coordL[r][k] = fmaxf(acc, 0.f);
    }
    for (int i = tid; i < NT * NSC; i += 512) { int r = i >> 5, k = i & 31; sceneL[r][k] = p.sd[(b * NT + r) * NSC + k]; }
    for (int i = tid; i < NT * NAG; i += 512) { int r = i >> 4, k = i & 15; agentL[r][k] = p.adata[(g * NT + r) * NAG + k] * relv; }
    if (tid < NTY) tyL[tid] = p.ty[g * NTY + tid];
    __syncthreads();
    const int c = tid;
    float base = p.vbase[c] + relv * p.vag[c];
    for (int i = 0; i < NTY; ++i) base += tyL[i] * p.Wty[i * 512 + c];
    const float vbeL = p.vbe[c];
    float acc[NT];
#pragma unroll
    for (int r = 0; r < NT; ++r) acc[r] = base + (r > 0 ? vbeL : 0.f);
    for (int k = 0; k < NH; ++k) { float w = p.W_ih[k * 512 + c];
#pragma unroll
        for (int r = 0; r < NT; ++r) acc[r] += coordL[r][k] * w; }
    for (int k = 0; k < NSC; ++k) { float w = p.Wsc[k * 512 + c];
#pragma unroll
        for (int r = 0; r < NT; ++r) acc[r] += sceneL[r][k] * w; }
    for (int k = 0; k < NAG; ++k) { float w = p.Wag[k * 512 + c];
#pragma unroll
        for (int r = 0; r < NT; ++r) acc[r] += agentL[r][k] * w; }
#pragma unroll
    for (int r = 0; r < NT; ++r) p.Xs[((size_t)(g * NT + r)) * 512 + c] = acc[r];
}

// ---- One recurrence step: 4 rows/block, 128 blocks x 1024 threads, fp32 ----
// Split-K everywhere; output projection fused (stage E).
__global__ __launch_bounds__(1024) void k_step(Params p, int t) {
    const int tid = threadIdx.x;
    const int r0 = blockIdx.x * 4;
    const int b = r0 >> 6;
    const int n = tid & 127;
    const int g8 = tid >> 7;                 // 0..7
    const float* __restrict__ hcur = (t & 1) ? p.h1 : p.h0;
    float* hnxt = (t & 1) ? p.h0 : p.h1;

    __shared__ float lh[4][NH], lR[4][NH], lse[4][NH];
    __shared__ float ps[16][NH];
    __shared__ float hsumL[NH], shw2[NH];
    __shared__ float lagg[4][NH];
    __shared__ float lgp[2][4][512];

    // (1) own-row state loads + batch hsum partials.
    if (tid < 512) {
        int rr = tid >> 7, k = tid & 127;
        lh[rr][k]  = hcur[(r0 + rr) * NH + k];
        lR[rr][k]  = p.R [(r0 + rr) * NH + k];
        lse[rr][k] = p.se[(r0 + rr) * NH + k];
    }
    if (t > 0) {
        float s = 0.f;
        const float* hb = hcur + (b * NA + g8 * 8) * NH + n;
#pragma unroll
        for (int j = 0; j < 8; ++j) s += hb[j * NH];
        ps[g8][n] = s;
    }
    __syncthreads();
    if (t > 0 && tid < NH) {
        float s = 0.f;
#pragma unroll
        for (int q = 0; q < 8; ++q) s += ps[q][tid];
        hsumL[tid] = s;
    }
    __syncthreads();
    if (t > 0) {
        float s = 0.f;
        const float* w2 = p.W_edge + NH * NH + n;
#pragma unroll
        for (int k = 16 * g8; k < 16 * g8 + 16; ++k) s += hsumL[k] * w2[k * NH];
        ps[g8][n] = s;
    }
    __syncthreads();
    if (tid < NH) {
        float s = 0.f;
        if (t > 0) {
#pragma unroll
            for (int q = 0; q < 8; ++q) s += ps[q][tid];
        }
        shw2[tid] = s;
    }
    __syncthreads();

    // Stage A: 8 groups = 4 paths x 2 row-pairs, full K=128 per thread.
    {
        const int path = g8 >> 1, rp = g8 & 1;
        const float* wb; const float* d0; const float* d1;
        if (path == 0)      { wb = p.W_edge + n;               d0 = lh[2 * rp];  d1 = lh[2 * rp + 1];  }
        else if (path == 1) { wb = p.W_edge + 2 * NH * NH + n; d0 = lR[2 * rp];  d1 = lR[2 * rp + 1];  }
        else if (path == 2) { wb = p.W_self + n;               d0 = lh[2 * rp];  d1 = lh[2 * rp + 1];  }
        else                { wb = p.W_self + NH * NH + n;     d0 = lse[2 * rp]; d1 = lse[2 * rp + 1]; }
        float a0 = 0.f, a1 = 0.f;
#pragma unroll 8
        for (int k = 0; k < NH; ++k) {
            float w = wb[k * NH];
            a0 += d0[k] * w; a1 += d1[k] * w;
        }
        ps[path * 4 + 2 * rp + 0][n] = a0;
        ps[path * 4 + 2 * rp + 1][n] = a1;
    }
    __syncthreads();
    // Combine: R_new, se_new, agg for 4 rows.
    if (tid < 512) {
        int rr = tid >> 7, k = tid & 127;
        float a1v = ps[0 + rr][k];                       // h@W1
        float a3v = ps[4 + rr][k];                       // R@W3
        float aSv = ps[8 + rr][k] + ps[12 + rr][k];      // h@Ws1 + se@Ws2
        float Rn = 64.f * a1v + shw2[k] + a3v + 64.f * p.b_edge[k];
        float Sn = aSv + p.sesty[(r0 + rr) * NH + k];
        p.R [(r0 + rr) * NH + k] = Rn;
        p.se[(r0 + rr) * NH + k] = Sn;
        lagg[rr][k] = Rn + Sn;
    }
    __syncthreads();

    // Stage C: gates; 512 cols x 2 K-halves, 4 rows per thread.
    {
        const int c = tid & 511, kh = tid >> 9;
        float a0 = 0.f, a1 = 0.f, a2 = 0.f, a3 = 0.f;
        if (kh == 0) {
            a0 = p.Xs[((size_t)(r0 + 0) * NT + t) * 512 + c];
            a1 = p.Xs[((size_t)(r0 + 1) * NT + t) * 512 + c];
            a2 = p.Xs[((size_t)(r0 + 2) * NT + t) * 512 + c];
            a3 = p.Xs[((size_t)(r0 + 3) * NT + t) * 512 + c];
        }
        if (t > 0) {
            const float* wc = p.Wcomb + c;
            const float* wh = p.W_hh + c;
#pragma unroll 8
            for (int k = 64 * kh; k < 64 * kh + 64; ++k) {
                float w = wc[k * 512];
                a0 += lagg[0][k] * w; a1 += lagg[1][k] * w;
                a2 += lagg[2][k] * w; a3 += lagg[3][k] * w;
            }
#pragma unroll 8
            for (int k = 64 * kh; k < 64 * kh + 64; ++k) {
                float w = wh[k * 512];
                a0 += lh[0][k] * w; a1 += lh[1][k] * w;
                a2 += lh[2][k] * w; a3 += lh[3][k] * w;
            }
        }
        lgp[kh][0][c] = a0; lgp[kh][1][c] = a1;
        lgp[kh][2][c] = a2; lgp[kh][3][c] = a3;
    }
    __syncthreads();

    // Stage D: combine K-halves + LSTM elementwise; h_new into lh.
    if (tid < 512) {
        const int rr = tid >> 7, k = tid & 127, g = r0 + rr;
        float gi = lgp[0][rr][k]          + lgp[1][rr][k];
        float gf = lgp[0][rr][NH + k]     + lgp[1][rr][NH + k];
        float gg = lgp[0][rr][2 * NH + k] + lgp[1][rr][2 * NH + k];
        float go = lgp[0][rr][3 * NH + k] + lgp[1][rr][3 * NH + k];
        float si = 1.f / (1.f + expf(-gi));
        float sf = 1.f / (1.f + expf(-gf));
        float so = 1.f / (1.f + expf(-go));
        float cn = sf * p.c[g * NH + k] + si * tanhf(gg);
        float hn = so * tanhf(cn);
        p.c[g * NH + k] = cn;
        hnxt[g * NH + k] = hn;
        lh[rr][k] = hn;
    }
    __syncthreads();

    // Stage E: fused out projection, split-K over kh; relu(h_new@W_pred + b_pred).
    {
        const int q = (tid >> 7) & 3, kh = tid >> 9;
        float s = 0.f;
        const float* wp = p.W_pred + n;
#pragma unroll 8
        for (int k = 64 * kh; k < 64 * kh + 64; ++k) s += lh[q][k] * wp[k * NH];
        ps[kh * 4 + q][n] = s;
    }
    __syncthreads();
    if (tid < 512) {
        const int q = tid >> 7, k = tid & 127;
        float v = ps[q][k] + ps[4 + q][k] + p.b_pred[k];
        p.out[((size_t)(r0 + q) * NT + t) * NH + k] = fmaxf(v, 0.f);
    }
}

extern "C" void kernel_launch(void* const* d_in, const int* in_sizes, int n_in,
                              void* d_out, int out_size, void* d_ws, size_t ws_size,
                              hipStream_t stream) {
    const float* const* in = (const float* const*)d_in;
    Params p;
    p.traj = in[0]; p.ntraj = in[1]; p.ty = in[2]; p.sd = in[3]; p.adata = in[4]; p.rel = in[5];
    p.W_in = in[6]; p.b_in = in[7]; p.W_nt = in[8]; p.b_nt = in[9];
    p.W_ag = in[10]; p.b_ag = in[11]; p.W_sc = in[12]; p.b_sc = in[13];
    p.W_ein = in[14]; p.b_ein = in[15]; p.W_ety = in[16]; p.b_ety = in[17];
    p.W_edge = in[18]; p.b_edge = in[19]; p.W_self = in[20]; p.b_self = in[21];
    p.W_e2n = in[22]; p.b_e2n = in[23];
    p.W_ih = in[24]; p.W_hh = in[25]; p.b_ih = in[26]; p.b_hh = in[27];
    p.W_pred = in[28]; p.b_pred = in[29];

    float* ws = (float*)d_ws;
    const size_t S = (size_t)NB * NA * NH;   // 65536
    p.h0 = ws;                // zeroed
    p.h1 = ws + S;            // zeroed
    p.c  = ws + 2 * S;        // zeroed
    p.se = ws + 3 * S;        // zeroed
    p.R  = ws + 4 * S;        // k_prelude
    float* w = ws + 5 * S;
    p.Wty   = w;              w += 8 * 512;
    p.Wsc   = w;              w += 32 * 512;
    p.Wag   = w;              w += 16 * 512;
    p.Wcomb = w;              w += 128 * 512;
    p.vbase = w;              w += 512;
    p.vag   = w;              w += 512;
    p.vbe   = w;              w += 512;
    p.sesty = w;              w += (size_t)NB * NA * NH;
    p.Xs    = w;              w += (size_t)NB * NA * NT * 512;
    p.out = (float*)d_out;

    hipMemsetAsync(p.h0, 0, 4 * S * sizeof(float), stream);   // h0,h1,c,se
    k_prelude<<<313, 512, 0, stream>>>(p);                     // fold | r0
    k_xstatic<<<NB * NA, 512, 0, stream>>>(p);
    for (int t = 0; t < NT; ++t)
        k_step<<<NB * NA / 4, 1024, 0, stream>>>(p, t);
}

// Round 9
// 191.494 us; speedup vs baseline: 1.3128x; 1.3128x over previous
//
#include <hip/hip_runtime.h>

constexpr int NB = 8, NA = 64, NT = 12, NH = 128, NTY = 8, NSC = 32, NAG = 16;

struct Params {
    const float *traj, *ntraj, *ty, *sd, *adata, *rel;
    const float *W_in, *b_in, *W_nt, *b_nt, *W_ag, *b_ag, *W_sc, *b_sc;
    const float *W_ein, *b_ein, *W_ety, *b_ety;
    const float *W_edge, *b_edge, *W_self, *b_self, *W_e2n, *b_e2n;
    const float *W_ih, *W_hh, *b_ih, *b_hh, *W_pred, *b_pred;
    float *h0, *h1, *c, *se, *R;
    float *Wty, *Wsc, *Wag, *Wcomb, *vbase, *vag, *vbe, *sesty, *Xs, *out;
};

// ---- Prelude: fold (blk 0-184) | r0+sesty+state-zero (blk 185-312, 4 rows/block) ----
// x layout for W_ih rows: [coord 0:128 | type 128:256 | node 256:384 | scene 384:512 | agent 512:640]
__global__ __launch_bounds__(512) void k_prelude(Params p) {
    const int blk = blockIdx.x, tid = threadIdx.x;
    if (blk < 185) {
        const int c = tid;
        __shared__ float lrow[NH];
        __shared__ float b1[NH], b2[NH], b3[NH], b4[NH];
        if (blk < 184) {
            const float* src; int ihoff, row; float* dst;
            if (blk < 8)       { row = blk;      src = p.W_nt  + row * NH; ihoff = 128; dst = p.Wty; }
            else if (blk < 40) { row = blk - 8;  src = p.W_sc  + row * NH; ihoff = 384; dst = p.Wsc; }
            else if (blk < 56) { row = blk - 40; src = p.W_ag  + row * NH; ihoff = 512; dst = p.Wag; }
            else               { row = blk - 56; src = p.W_e2n + row * NH; ihoff = 256; dst = p.Wcomb; }
            if (c < NH) lrow[c] = src[c];
            __syncthreads();
            float acc = 0.f;
            for (int k = 0; k < NH; ++k) acc += lrow[k] * p.W_ih[(ihoff + k) * 512 + c];
            dst[row * 512 + c] = acc;
        } else {
            if (c < NH) { b1[c] = p.b_nt[c]; b2[c] = p.b_sc[c]; b3[c] = p.b_ag[c]; b4[c] = p.b_e2n[c]; }
            __syncthreads();
            float vb = p.b_ih[c] + p.b_hh[c], va = 0.f, ve = 0.f;
            for (int k = 0; k < NH; ++k) {
                vb += b1[k] * p.W_ih[(128 + k) * 512 + c] + b2[k] * p.W_ih[(384 + k) * 512 + c];
                va += b3[k] * p.W_ih[(512 + k) * 512 + c];
                ve += b4[k] * p.W_ih[(256 + k) * 512 + c];
            }
            p.vbase[c] = vb; p.vag[c] = va; p.vbe[c] = ve;
        }
    } else {
        // R0 closed form + sesty + zero-init h0/c/se, 4 rows/block.
        const int r0g = (blk - 185) * 4;
        const int b = r0g >> 6;
        const int q = tid >> 7, n = tid & 127;
        const int row = r0g + q, i = row & 63;
        __shared__ float lf[NA][6];
        __shared__ float lt[NA][NTY];
        __shared__ float sumf[6], sumt[NTY];
        if (tid < NA) {
            int j = tid, rj = b * NA + j;
            for (int k = 0; k < 3; ++k) {
                lf[j][k]     = p.ntraj[(rj * NT + 0) * 3 + k];
                lf[j][3 + k] = p.traj [(rj * NT + 0) * 3 + k];
            }
            for (int k = 0; k < NTY; ++k) lt[j][k] = p.ty[rj * NTY + k];
        }
        // zero-init carried state (replaces hipMemsetAsync fill)
        p.h0[row * NH + n] = 0.f;
        p.c [row * NH + n] = 0.f;
        p.se[row * NH + n] = 0.f;
        __syncthreads();
        if (tid < 6) {
            float s = 0.f; for (int j = 0; j < NA; ++j) s += lf[j][tid];
            sumf[tid] = s;
        } else if (tid < 6 + NTY) {
            int k = tid - 6; float s = 0.f;
            for (int j = 0; j < NA; ++j) s += lt[j][k];
            sumt[k] = s;
        }
        __syncthreads();
        float acc_i = p.b_ein[n] + p.b_ety[n];
        for (int k = 0; k < 6; ++k)   acc_i += lf[i][k] * p.W_ein[k * NH + n];
        for (int k = 0; k < NTY; ++k) acc_i += lt[i][k] * (p.W_ein[(12 + k) * NH + n] + p.W_ety[k * NH + n]);
        float acc_j = 0.f;
        for (int k = 0; k < 6; ++k)   acc_j += sumf[k] * p.W_ein[(6 + k) * NH + n];
        for (int k = 0; k < NTY; ++k) acc_j += sumt[k] * (p.W_ein[(20 + k) * NH + n] + p.W_ety[(NTY + k) * NH + n]);
        p.R[row * NH + n] = 64.f * acc_i + acc_j;
        float sv = p.b_self[n];
        for (int k = 0; k < NTY; ++k) sv += lt[i][k] * p.W_self[(2 * NH + k) * NH + n];
        p.sesty[row * NH + n] = sv;
    }
}

// ---- X_static[(g,t), 512]; vbe folded in for t>0 ----
__global__ __launch_bounds__(512) void k_xstatic(Params p) {
    const int g = blockIdx.x, tid = threadIdx.x, b = g >> 6;
    __shared__ float coordL[NT][NH];
    __shared__ float sceneL[NT][NSC];
    __shared__ float agentL[NT][NAG];
    __shared__ float tyL[NTY];
    const float relv = p.rel[g];
    for (int idx = tid; idx < NT * NH; idx += 512) {
        int r = idx >> 7, k = idx & 127;
        float acc = p.b_in[k];
        const float* nt = p.ntraj + (g * NT + r) * 3;
        const float* tr = p.traj  + (g * NT + r) * 3;
        for (int j = 0; j < 3; ++j) acc += nt[j] * p.W_in[j * NH + k] + tr[j] * p.W_in[(3 + j) * NH + k];
        coordL[r][k] = fmaxf(acc, 0.f);
    }
    for (int i = tid; i < NT * NSC; i += 512) { int r = i >> 5, k = i & 31; sceneL[r][k] = p.sd[(b * NT + r) * NSC + k]; }
    for (int i = tid; i < NT * NAG; i += 512) { int r = i >> 4, k = i & 15; agentL[r][k] = p.adata[(g * NT + r) * NAG + k] * relv; }
    if (tid < NTY) tyL[tid] = p.ty[g * NTY + tid];
    __syncthreads();
    const int c = tid;
    float base = p.vbase[c] + relv * p.vag[c];
    for (int i = 0; i < NTY; ++i) base += tyL[i] * p.Wty[i * 512 + c];
    const float vbeL = p.vbe[c];
    float acc[NT];
#pragma unroll
    for (int r = 0; r < NT; ++r) acc[r] = base + (r > 0 ? vbeL : 0.f);
    for (int k = 0; k < NH; ++k) { float w = p.W_ih[k * 512 + c];
#pragma unroll
        for (int r = 0; r < NT; ++r) acc[r] += coordL[r][k] * w; }
    for (int k = 0; k < NSC; ++k) { float w = p.Wsc[k * 512 + c];
#pragma unroll
        for (int r = 0; r < NT; ++r) acc[r] += sceneL[r][k] * w; }
    for (int k = 0; k < NAG; ++k) { float w = p.Wag[k * 512 + c];
#pragma unroll
        for (int r = 0; r < NT; ++r) acc[r] += agentL[r][k] * w; }
#pragma unroll
    for (int r = 0; r < NT; ++r) p.Xs[((size_t)(g * NT + r)) * 512 + c] = acc[r];
}

// ---- One recurrence step: 2 rows/block, 256 blocks x 1024 threads, fp32 ----
// Split-K; fused output projection; 6 barriers.
__global__ __launch_bounds__(1024) void k_step(Params p, int t) {
    const int tid = threadIdx.x;
    const int r0 = blockIdx.x * 2;
    const int b = r0 >> 6;
    const int n = tid & 127;
    const int g8 = tid >> 7;                 // 0..7
    const float* __restrict__ hcur = (t & 1) ? p.h1 : p.h0;
    float* hnxt = (t & 1) ? p.h0 : p.h1;

    __shared__ float lh[2][NH], lR[2][NH], lse[2][NH];
    __shared__ float psum[8][NH];            // batch h-sum partials
    __shared__ float ps2[8][NH];             // shw2 partials
    __shared__ float ps[16][NH];             // stage A / stage E partials
    __shared__ float lagg[2][NH];
    __shared__ float lgp[2][2][512];

    // Phase 0: own-row state loads + batch h-sum partials.
    if (tid < 256) {
        int rr = tid >> 7, k = tid & 127;
        lh[rr][k]  = hcur[(r0 + rr) * NH + k];
        lR[rr][k]  = p.R [(r0 + rr) * NH + k];
        lse[rr][k] = p.se[(r0 + rr) * NH + k];
    }
    if (t > 0) {
        float s = 0.f;
        const float* hb = hcur + (b * NA + g8 * 8) * NH + n;
#pragma unroll
        for (int j = 0; j < 8; ++j) s += hb[j * NH];
        psum[g8][n] = s;
    }
    __syncthreads();                          // B1

    // Phase 1: shw2 partials (from psum directly) + stage A partials.
    if (t > 0) {
        float s = 0.f;
        const float* w2 = p.W_edge + NH * NH + n;
#pragma unroll
        for (int k = 16 * g8; k < 16 * g8 + 16; ++k) {
            float hv = psum[0][k] + psum[1][k] + psum[2][k] + psum[3][k]
                     + psum[4][k] + psum[5][k] + psum[6][k] + psum[7][k];
            s += hv * w2[k * NH];
        }
        ps2[g8][n] = s;
    }
    {
        const int path = g8 >> 1, kh = g8 & 1;
        const float* wb; const float* d0; const float* d1;
        if (path == 0)      { wb = p.W_edge + n;               d0 = lh[0];  d1 = lh[1];  }
        else if (path == 1) { wb = p.W_edge + 2 * NH * NH + n; d0 = lR[0];  d1 = lR[1];  }
        else if (path == 2) { wb = p.W_self + n;               d0 = lh[0];  d1 = lh[1];  }
        else                { wb = p.W_self + NH * NH + n;     d0 = lse[0]; d1 = lse[1]; }
        float a0 = 0.f, a1 = 0.f;
#pragma unroll 8
        for (int k = 64 * kh; k < 64 * kh + 64; ++k) {
            float w = wb[k * NH];
            a0 += d0[k] * w; a1 += d1[k] * w;
        }
        ps[g8 * 2 + 0][n] = a0;               // = [path*4 + kh*2 + row]
        ps[g8 * 2 + 1][n] = a1;
    }
    __syncthreads();                          // B2

    // Phase 2: combine shw2 + R_new/se_new/agg.
    if (tid < 256) {
        int rr = tid >> 7, k = tid & 127;
        float shw2v = 0.f;
        if (t > 0) {
#pragma unroll
            for (int q = 0; q < 8; ++q) shw2v += ps2[q][k];
        }
        float a1v = ps[0 + rr][k] + ps[2 + rr][k];
        float a3v = ps[4 + rr][k] + ps[6 + rr][k];
        float aSv = ps[8 + rr][k] + ps[10 + rr][k]
                  + ps[12 + rr][k] + ps[14 + rr][k];
        float Rn = 64.f * a1v + shw2v + a3v + 64.f * p.b_edge[k];
        float Sn = aSv + p.sesty[(r0 + rr) * NH + k];
        p.R [(r0 + rr) * NH + k] = Rn;
        p.se[(r0 + rr) * NH + k] = Sn;
        lagg[rr][k] = Rn + Sn;
    }
    __syncthreads();                          // B3

    // Phase 3: gates; 512 cols x 2 K-halves, both rows per thread.
    {
        const int c = tid & 511, kh2 = tid >> 9;
        float a0 = 0.f, a1v = 0.f;
        if (kh2 == 0) {
            a0  = p.Xs[((size_t)r0 * NT + t) * 512 + c];
            a1v = p.Xs[((size_t)(r0 + 1) * NT + t) * 512 + c];
        }
        if (t > 0) {
            const float* wc = p.Wcomb + c;
            const float* wh = p.W_hh + c;
#pragma unroll 8
            for (int k = 64 * kh2; k < 64 * kh2 + 64; ++k) {
                float w = wc[k * 512];
                a0 += lagg[0][k] * w; a1v += lagg[1][k] * w;
            }
#pragma unroll 8
            for (int k = 64 * kh2; k < 64 * kh2 + 64; ++k) {
                float w = wh[k * 512];
                a0 += lh[0][k] * w; a1v += lh[1][k] * w;
            }
        }
        lgp[kh2][0][c] = a0;
        lgp[kh2][1][c] = a1v;
    }
    __syncthreads();                          // B4

    // Phase 4: combine K-halves + LSTM elementwise; h_new into lh + hnxt.
    if (tid < 256) {
        const int rr = tid >> 7, k = tid & 127, g = r0 + rr;
        float gi = lgp[0][rr][k]          + lgp[1][rr][k];
        float gf = lgp[0][rr][NH + k]     + lgp[1][rr][NH + k];
        float gg = lgp[0][rr][2 * NH + k] + lgp[1][rr][2 * NH + k];
        float go = lgp[0][rr][3 * NH + k] + lgp[1][rr][3 * NH + k];
        float si = 1.f / (1.f + expf(-gi));
        float sf = 1.f / (1.f + expf(-gf));
        float so = 1.f / (1.f + expf(-go));
        float cn = sf * p.c[g * NH + k] + si * tanhf(gg);
        float hn = so * tanhf(cn);
        p.c[g * NH + k] = cn;
        hnxt[g * NH + k] = hn;
        lh[rr][k] = hn;
    }
    __syncthreads();                          // B5

    // Phase 5: fused out projection; sel = (kq<<1)|r, K-slices of 32.
    {
        const int r = g8 & 1, kq = g8 >> 1;
        float s = 0.f;
        const float* wp = p.W_pred + n;
#pragma unroll
        for (int k = 32 * kq; k < 32 * kq + 32; ++k) s += lh[r][k] * wp[k * NH];
        ps[g8][n] = s;
    }
    __syncthreads();                          // B6
    if (tid < 256) {
        const int rr = tid >> 7, k = tid & 127;
        float v = ps[rr][k] + ps[2 + rr][k] + ps[4 + rr][k] + ps[6 + rr][k] + p.b_pred[k];
        p.out[((size_t)(r0 + rr) * NT + t) * NH + k] = fmaxf(v, 0.f);
    }
}

extern "C" void kernel_launch(void* const* d_in, const int* in_sizes, int n_in,
                              void* d_out, int out_size, void* d_ws, size_t ws_size,
                              hipStream_t stream) {
    const float* const* in = (const float* const*)d_in;
    Params p;
    p.traj = in[0]; p.ntraj = in[1]; p.ty = in[2]; p.sd = in[3]; p.adata = in[4]; p.rel = in[5];
    p.W_in = in[6]; p.b_in = in[7]; p.W_nt = in[8]; p.b_nt = in[9];
    p.W_ag = in[10]; p.b_ag = in[11]; p.W_sc = in[12]; p.b_sc = in[13];
    p.W_ein = in[14]; p.b_ein = in[15]; p.W_ety = in[16]; p.b_ety = in[17];
    p.W_edge = in[18]; p.b_edge = in[19]; p.W_self = in[20]; p.b_self = in[21];
    p.W_e2n = in[22]; p.b_e2n = in[23];
    p.W_ih = in[24]; p.W_hh = in[25]; p.b_ih = in[26]; p.b_hh = in[27];
    p.W_pred = in[28]; p.b_pred = in[29];

    float* ws = (float*)d_ws;
    const size_t S = (size_t)NB * NA * NH;   // 65536
    p.h0 = ws;                // zeroed by k_prelude
    p.h1 = ws + S;            // written at t=0 before any read
    p.c  = ws + 2 * S;        // zeroed by k_prelude
    p.se = ws + 3 * S;        // zeroed by k_prelude
    p.R  = ws + 4 * S;        // k_prelude
    float* w = ws + 5 * S;
    p.Wty   = w;              w += 8 * 512;
    p.Wsc   = w;              w += 32 * 512;
    p.Wag   = w;              w += 16 * 512;
    p.Wcomb = w;              w += 128 * 512;
    p.vbase = w;              w += 512;
    p.vag   = w;              w += 512;
    p.vbe   = w;              w += 512;
    p.sesty = w;              w += (size_t)NB * NA * NH;
    p.Xs    = w;              w += (size_t)NB * NA * NT * 512;
    p.out = (float*)d_out;

    k_prelude<<<313, 512, 0, stream>>>(p);                     // fold | r0 | state-zero
    k_xstatic<<<NB * NA, 512, 0, stream>>>(p);
    for (int t = 0; t < NT; ++t)
        k_step<<<NB * NA / 2, 1024, 0, stream>>>(p, t);
}